// Round 1
// baseline (1564.314 us; speedup 1.0000x reference)
//
#include <hip/hip_runtime.h>

typedef __bf16 bf16;
typedef __bf16 bf16x8 __attribute__((ext_vector_type(8)));
typedef float  f32x4  __attribute__((ext_vector_type(4)));

#define EPSF 1e-5f

__device__ __forceinline__ float bf2f(bf16 x) { return (float)x; }
__device__ __forceinline__ bf16  f2bf(float x) { return (bf16)x; }
__device__ __forceinline__ float siluf(float x) { return x / (1.f + expf(-x)); }

// ---------------------------------------------------------------------------
// Weight prepack: W[K][N] f32 -> WT_hi[N][K], WT_lo[N][K] bf16 (hi/lo split).
// 7 segments in one launch (grid.y = segment).
// ---------------------------------------------------------------------------
struct PrepackArgs {
    const float* W[7];
    bf16* TH[7];
    bf16* TL[7];
    int K[7];
    int N[7];
};

__global__ __launch_bounds__(256) void prepack_kernel(PrepackArgs a)
{
    int s = blockIdx.y;
    int idx = blockIdx.x * 256 + threadIdx.x;
    int K = a.K[s], N = a.N[s];
    if (idx >= K * N) return;
    int k = idx / N, n = idx - k * N;
    float v = a.W[s][idx];
    bf16 hi = f2bf(v);
    a.TH[s][(size_t)n * K + k] = hi;
    a.TL[s][(size_t)n * K + k] = f2bf(v - bf2f(hi));
}

// ---------------------------------------------------------------------------
// Split-bf16 MFMA GEMM. A: hi/lo planes (AH/AL) or f32 (Af, packed in regs
// then vector LDS stores). B: prepacked transposed hi/lo (L2-resident),
// next-tile prefetched. acc += aH*bH + aH*bL + aL*bH.
// Tile 128(M) x 64(N), BK=32, 256 thr = 4 waves (2M x 2N).
// ---------------------------------------------------------------------------
__global__ __launch_bounds__(256) void gemm_hl(
    const bf16* __restrict__ AH, const bf16* __restrict__ AL,
    const float* __restrict__ Af, int lda,
    const bf16* __restrict__ WTh, const bf16* __restrict__ WTl,
    const float* __restrict__ bias,
    int N, int K,
    float* __restrict__ outF, int ldF,
    bf16* __restrict__ outB, int ldB,
    bf16* __restrict__ outH, bf16* __restrict__ outL, int ldH,
    int doGelu,
    const float* __restrict__ dtb, const float* __restrict__ Alog,
    float* __restrict__ dtf, float* __restrict__ dAf)
{
    __shared__ bf16 As [128][40];
    __shared__ bf16 Als[128][40];

    const int tid  = threadIdx.x;
    const int lane = tid & 63;
    const int wid  = tid >> 6;
    const int waveM = wid & 1, waveN = wid >> 1;
    const int m16 = lane & 15, quad = lane >> 4;
    const int row0 = blockIdx.x * 128;
    const int n0   = blockIdx.y * 64;

    f32x4 acc[4][2];
#pragma unroll
    for (int i = 0; i < 4; ++i)
#pragma unroll
        for (int j = 0; j < 2; ++j)
            acc[i][j] = (f32x4){0.f, 0.f, 0.f, 0.f};

    const int ar = tid >> 1, akc = (tid & 1) * 16;  // A staging: row, k-chunk

    const int bn0 = min(n0 + waveN * 32 + m16,      N - 1);
    const int bn1 = min(n0 + waveN * 32 + 16 + m16, N - 1);
    const bf16* bH0p = WTh + (size_t)bn0 * K + quad * 8;
    const bf16* bH1p = WTh + (size_t)bn1 * K + quad * 8;
    const bf16* bL0p = WTl + (size_t)bn0 * K + quad * 8;
    const bf16* bL1p = WTl + (size_t)bn1 * K + quad * 8;

    bf16x8 bH[2], bL[2], bHn[2], bLn[2];
    bH[0] = *(const bf16x8*)(bH0p);
    bH[1] = *(const bf16x8*)(bH1p);
    bL[0] = *(const bf16x8*)(bL0p);
    bL[1] = *(const bf16x8*)(bL1p);

    for (int k0 = 0; k0 < K; k0 += 32) {
        // ---- stage A tile 128x32 ----
        if (AH) {
            const bf16* s0 = AH + (size_t)(row0 + ar) * lda + k0 + akc;
            const bf16* s1 = AL + (size_t)(row0 + ar) * lda + k0 + akc;
            *(uint4*)&As [ar][akc]     = *(const uint4*)s0;
            *(uint4*)&As [ar][akc + 8] = *(const uint4*)(s0 + 8);
            *(uint4*)&Als[ar][akc]     = *(const uint4*)s1;
            *(uint4*)&Als[ar][akc + 8] = *(const uint4*)(s1 + 8);
        } else {
            const float* asrc = Af + (size_t)(row0 + ar) * lda + k0 + akc;
            float f[16];
            *(float4*)&f[0]  = ((const float4*)asrc)[0];
            *(float4*)&f[4]  = ((const float4*)asrc)[1];
            *(float4*)&f[8]  = ((const float4*)asrc)[2];
            *(float4*)&f[12] = ((const float4*)asrc)[3];
            bf16 hv[16], lv[16];
#pragma unroll
            for (int c = 0; c < 16; ++c) {
                bf16 hi = f2bf(f[c]);
                hv[c] = hi;
                lv[c] = f2bf(f[c] - bf2f(hi));
            }
            *(uint4*)&As [ar][akc]     = *(uint4*)&hv[0];
            *(uint4*)&As [ar][akc + 8] = *(uint4*)&hv[8];
            *(uint4*)&Als[ar][akc]     = *(uint4*)&lv[0];
            *(uint4*)&Als[ar][akc + 8] = *(uint4*)&lv[8];
        }
        __syncthreads();

        // ---- prefetch next k-tile's B fragments (global, L2-hot) ----
        const bool more = (k0 + 32) < K;
        if (more) {
            int kn = k0 + 32;
            bHn[0] = *(const bf16x8*)(bH0p + kn);
            bHn[1] = *(const bf16x8*)(bH1p + kn);
            bLn[0] = *(const bf16x8*)(bL0p + kn);
            bLn[1] = *(const bf16x8*)(bL1p + kn);
        }

        // ---- LDS -> A fragments ----
        bf16x8 aH[4], aL[4];
#pragma unroll
        for (int mi = 0; mi < 4; ++mi) {
            aH[mi] = *(const bf16x8*)&As [waveM * 64 + mi * 16 + m16][quad * 8];
            aL[mi] = *(const bf16x8*)&Als[waveM * 64 + mi * 16 + m16][quad * 8];
        }

#pragma unroll
        for (int mi = 0; mi < 4; ++mi)
#pragma unroll
            for (int ni = 0; ni < 2; ++ni) {
                acc[mi][ni] = __builtin_amdgcn_mfma_f32_16x16x32_bf16(
                    aH[mi], bH[ni], acc[mi][ni], 0, 0, 0);
                acc[mi][ni] = __builtin_amdgcn_mfma_f32_16x16x32_bf16(
                    aH[mi], bL[ni], acc[mi][ni], 0, 0, 0);
                acc[mi][ni] = __builtin_amdgcn_mfma_f32_16x16x32_bf16(
                    aL[mi], bH[ni], acc[mi][ni], 0, 0, 0);
            }
        __syncthreads();

        if (more) {
            bH[0] = bHn[0]; bH[1] = bHn[1];
            bL[0] = bLn[0]; bL[1] = bLn[1];
        }
    }

    // ---- epilogue ----
#pragma unroll
    for (int ni = 0; ni < 2; ++ni) {
        int col = n0 + waveN * 32 + ni * 16 + m16;
        if (col >= N) continue;
        float bv = bias ? bias[col] : 0.f;
#pragma unroll
        for (int mi = 0; mi < 4; ++mi) {
#pragma unroll
            for (int r = 0; r < 4; ++r) {
                int row = row0 + waveM * 64 + mi * 16 + quad * 4 + r;
                float v = acc[mi][ni][r] + bv;
                if (dtf && col >= 1088) {
                    int head = col - 1088;
                    float xx = v + dtb[head];
                    float sp = (xx > 20.f) ? xx : log1pf(expf(xx));
                    float A  = -expf(Alog[head]);
                    dtf[(size_t)row * 16 + head] = sp;
                    dAf[(size_t)row * 16 + head] = expf(sp * A);
                } else {
                    if (doGelu) v = 0.5f * v * (1.f + erff(v * 0.70710678118654752f));
                    if (outB) outB[(size_t)row * ldB + col] = f2bf(v);
                    if (outF) outF[(size_t)row * ldF + col] = v;
                    if (outH) {
                        bf16 hi = f2bf(v);
                        outH[(size_t)row * ldH + col] = hi;
                        outL[(size_t)row * ldH + col] = f2bf(v - bf2f(hi));
                    }
                }
            }
        }
    }
}

// ---------------------------------------------------------------------------
// Causal depthwise conv (K=4) + bias + silu over xBC = zx[:, 512:1088].
// One thread per (row, 8-channel block): bf16x8 loads, float4 stores.
// grid = M*72/256 blocks of 256.
// ---------------------------------------------------------------------------
__global__ __launch_bounds__(256) void conv_kernel(
    const bf16* __restrict__ zx,     // 32768 x 1104
    const float* __restrict__ cw,    // 576 x 4
    const float* __restrict__ cbias, // 576
    float* __restrict__ xs,          // 32768 x 512
    float* __restrict__ Bc,          // 32768 x 32
    float* __restrict__ Cc)          // 32768 x 32
{
    int g = blockIdx.x * 256 + threadIdx.x;
    if (g >= 32768 * 72) return;
    int row = g / 72;
    int cb8 = g - row * 72;          // 0..71 (8-channel block)
    int ch  = cb8 * 8;               // 0..568
    int l   = row & 2047;

    float4 wv[8];
#pragma unroll
    for (int c = 0; c < 8; ++c)
        wv[c] = *(const float4*)(cw + (ch + c) * 4);

    float acc[8];
    {
        float4 b0 = *(const float4*)(cbias + ch);
        float4 b1 = *(const float4*)(cbias + ch + 4);
        acc[0] = b0.x; acc[1] = b0.y; acc[2] = b0.z; acc[3] = b0.w;
        acc[4] = b1.x; acc[5] = b1.y; acc[6] = b1.z; acc[7] = b1.w;
    }

#pragma unroll
    for (int i = 0; i < 4; ++i) {
        int ls = l + i - 3;
        if (ls >= 0) {
            bf16x8 v = *(const bf16x8*)(zx + (size_t)(row + i - 3) * 1104 + 512 + ch);
#pragma unroll
            for (int c = 0; c < 8; ++c)
                acc[c] = fmaf(bf2f(v[c]), (&wv[c].x)[i], acc[c]);
        }
    }

    float s[8];
#pragma unroll
    for (int c = 0; c < 8; ++c) s[c] = siluf(acc[c]);

    if (cb8 < 64) {
        float* dst = xs + (size_t)row * 512 + ch;
        ((float4*)dst)[0] = (float4){s[0], s[1], s[2], s[3]};
        ((float4*)dst)[1] = (float4){s[4], s[5], s[6], s[7]};
    } else if (cb8 < 68) {
        float* dst = Bc + (size_t)row * 32 + (ch - 512);
        ((float4*)dst)[0] = (float4){s[0], s[1], s[2], s[3]};
        ((float4*)dst)[1] = (float4){s[4], s[5], s[6], s[7]};
    } else {
        float* dst = Cc + (size_t)row * 32 + (ch - 544);
        ((float4*)dst)[0] = (float4){s[0], s[1], s[2], s[3]};
        ((float4*)dst)[1] = (float4){s[4], s[5], s[6], s[7]};
    }
}

// ---------------------------------------------------------------------------
// Chunked SSM scan, Q=64, 32 chunks per (b,h). 4 chunks (waves) per block.
// ---------------------------------------------------------------------------
#define QCH   64
#define NCH   32

struct StepB  { float Bv[16]; float da, dtv, xv; };
struct StepBC { float Bv[16]; float Cv[16]; float da, dtv, xv; };

__device__ __forceinline__ void load_stepB(
    StepB& S, const float* Bc, const float* dtf, const float* dAf,
    const float* xs, size_t r, int h, int p, int nb)
{
    const float4* bp = (const float4*)(Bc + r * 32 + nb);
    *(float4*)&S.Bv[0]  = bp[0];
    *(float4*)&S.Bv[4]  = bp[1];
    *(float4*)&S.Bv[8]  = bp[2];
    *(float4*)&S.Bv[12] = bp[3];
    S.da  = dAf[r * 16 + h];
    S.dtv = dtf[r * 16 + h];
    S.xv  = xs[r * 512 + h * 32 + p];
}

__device__ __forceinline__ void load_stepBC(
    StepBC& S, const float* Bc, const float* Cc, const float* dtf,
    const float* dAf, const float* xs, size_t r, int h, int p, int nb)
{
    const float4* bp = (const float4*)(Bc + r * 32 + nb);
    *(float4*)&S.Bv[0]  = bp[0];
    *(float4*)&S.Bv[4]  = bp[1];
    *(float4*)&S.Bv[8]  = bp[2];
    *(float4*)&S.Bv[12] = bp[3];
    const float4* cp = (const float4*)(Cc + r * 32 + nb);
    *(float4*)&S.Cv[0]  = cp[0];
    *(float4*)&S.Cv[4]  = cp[1];
    *(float4*)&S.Cv[8]  = cp[2];
    *(float4*)&S.Cv[12] = cp[3];
    S.da  = dAf[r * 16 + h];
    S.dtv = dtf[r * 16 + h];
    S.xv  = xs[r * 512 + h * 32 + p];
}

__global__ __launch_bounds__(256) void scan_phase1(
    const float* __restrict__ xs,
    const float* __restrict__ Bc,
    const float* __restrict__ dtf,
    const float* __restrict__ dAf,
    float* __restrict__ cs,         // 8192 x 1024
    float* __restrict__ cp)         // 8192
{
    int blk = blockIdx.x * 4 + (threadIdx.x >> 6);
    int bh = blk >> 5, c = blk & (NCH - 1);
    int b = bh >> 4, h = bh & 15;
    int lane = threadIdx.x & 63;
    int p = lane & 31, half = lane >> 5, nb = half * 16;
    float hs[16];
#pragma unroll
    for (int j = 0; j < 16; ++j) hs[j] = 0.f;
    float P = 1.f;
    size_t rb = (size_t)b * 2048 + (size_t)c * QCH;

    StepB S0, S1;
    load_stepB(S0, Bc, dtf, dAf, xs, rb, h, p, nb);

    for (int t = 0; t < QCH; t += 2) {
        load_stepB(S1, Bc, dtf, dAf, xs, rb + t + 1, h, p, nb);
        {
            float dtx = S0.dtv * S0.xv, da = S0.da;
#pragma unroll
            for (int j = 0; j < 16; ++j)
                hs[j] = fmaf(hs[j], da, dtx * S0.Bv[j]);
            P *= da;
        }
        if (t + 2 < QCH)
            load_stepB(S0, Bc, dtf, dAf, xs, rb + t + 2, h, p, nb);
        {
            float dtx = S1.dtv * S1.xv, da = S1.da;
#pragma unroll
            for (int j = 0; j < 16; ++j)
                hs[j] = fmaf(hs[j], da, dtx * S1.Bv[j]);
            P *= da;
        }
    }

    float* dst = cs + (size_t)blk * 1024 + lane * 16;
#pragma unroll
    for (int q = 0; q < 4; ++q)
        ((float4*)dst)[q] = (float4){hs[q*4], hs[q*4+1], hs[q*4+2], hs[q*4+3]};
    if (lane == 0) cp[blk] = P;
}

__global__ __launch_bounds__(64) void scan_phase2(
    float* __restrict__ cs,
    const float* __restrict__ cp)
{
    int bh = blockIdx.x;
    int lane = threadIdx.x;
    float H[16];
#pragma unroll
    for (int j = 0; j < 16; ++j) H[j] = 0.f;
    for (int c = 0; c < NCH; ++c) {
        float* base = cs + ((size_t)(bh * NCH + c)) * 1024 + lane * 16;
        float E[16];
#pragma unroll
        for (int q = 0; q < 4; ++q) {
            float4 v = ((const float4*)base)[q];
            E[q*4] = v.x; E[q*4+1] = v.y; E[q*4+2] = v.z; E[q*4+3] = v.w;
        }
        float P = cp[bh * NCH + c];
#pragma unroll
        for (int q = 0; q < 4; ++q)
            ((float4*)base)[q] = (float4){H[q*4], H[q*4+1], H[q*4+2], H[q*4+3]};
#pragma unroll
        for (int j = 0; j < 16; ++j)
            H[j] = fmaf(H[j], P, E[j]);
    }
}

__global__ __launch_bounds__(256) void scan_phase3(
    const float* __restrict__ xs,
    const float* __restrict__ Bc,
    const float* __restrict__ Cc,
    const float* __restrict__ dtf,
    const float* __restrict__ dAf,
    const float* __restrict__ Dv,
    const float* __restrict__ cs,
    bf16* __restrict__ zx)          // y -> zx cols [512,1024)
{
    int blk = blockIdx.x * 4 + (threadIdx.x >> 6);
    int bh = blk >> 5, c = blk & (NCH - 1);
    int b = bh >> 4, h = bh & 15;
    int lane = threadIdx.x & 63;
    int p = lane & 31, half = lane >> 5, nb = half * 16;
    float Dh = Dv[h];
    float hs[16];
    {
        const float* src = cs + (size_t)blk * 1024 + lane * 16;
#pragma unroll
        for (int q = 0; q < 4; ++q) {
            float4 v = ((const float4*)src)[q];
            hs[q*4] = v.x; hs[q*4+1] = v.y; hs[q*4+2] = v.z; hs[q*4+3] = v.w;
        }
    }
    size_t rb = (size_t)b * 2048 + (size_t)c * QCH;

    StepBC S0, S1;
    load_stepBC(S0, Bc, Cc, dtf, dAf, xs, rb, h, p, nb);

    for (int t = 0; t < QCH; t += 2) {
        load_stepBC(S1, Bc, Cc, dtf, dAf, xs, rb + t + 1, h, p, nb);
        {
            float dtx = S0.dtv * S0.xv, da = S0.da;
            float y0 = 0.f, y1 = 0.f, y2 = 0.f, y3 = 0.f;
#pragma unroll
            for (int j = 0; j < 16; j += 4) {
                hs[j]   = fmaf(hs[j],   da, dtx * S0.Bv[j]);   y0 = fmaf(hs[j],   S0.Cv[j],   y0);
                hs[j+1] = fmaf(hs[j+1], da, dtx * S0.Bv[j+1]); y1 = fmaf(hs[j+1], S0.Cv[j+1], y1);
                hs[j+2] = fmaf(hs[j+2], da, dtx * S0.Bv[j+2]); y2 = fmaf(hs[j+2], S0.Cv[j+2], y2);
                hs[j+3] = fmaf(hs[j+3], da, dtx * S0.Bv[j+3]); y3 = fmaf(hs[j+3], S0.Cv[j+3], y3);
            }
            float yv = (y0 + y1) + (y2 + y3);
            yv += __shfl_xor(yv, 32);
            if (half == 0)
                zx[(rb + t) * 1104 + 512 + h * 32 + p] = f2bf(yv + Dh * S0.xv);
        }
        if (t + 2 < QCH)
            load_stepBC(S0, Bc, Cc, dtf, dAf, xs, rb + t + 2, h, p, nb);
        {
            float dtx = S1.dtv * S1.xv, da = S1.da;
            float y0 = 0.f, y1 = 0.f, y2 = 0.f, y3 = 0.f;
#pragma unroll
            for (int j = 0; j < 16; j += 4) {
                hs[j]   = fmaf(hs[j],   da, dtx * S1.Bv[j]);   y0 = fmaf(hs[j],   S1.Cv[j],   y0);
                hs[j+1] = fmaf(hs[j+1], da, dtx * S1.Bv[j+1]); y1 = fmaf(hs[j+1], S1.Cv[j+1], y1);
                hs[j+2] = fmaf(hs[j+2], da, dtx * S1.Bv[j+2]); y2 = fmaf(hs[j+2], S1.Cv[j+2], y2);
                hs[j+3] = fmaf(hs[j+3], da, dtx * S1.Bv[j+3]); y3 = fmaf(hs[j+3], S1.Cv[j+3], y3);
            }
            float yv = (y0 + y1) + (y2 + y3);
            yv += __shfl_xor(yv, 32);
            if (half == 0)
                zx[(rb + t + 1) * 1104 + 512 + h * 32 + p] = f2bf(yv + Dh * S1.xv);
        }
    }
}

// ---------------------------------------------------------------------------
// normed = rmsnorm(y * silu(z), nw) over 512 -> hi/lo bf16 planes.
// y lives in zx cols [512,1024); z in cols [0,512). 4 rows per block.
// ---------------------------------------------------------------------------
__global__ __launch_bounds__(256) void gaterms_kernel(
    const bf16* __restrict__ zx,     // 32768 x 1104
    const float* __restrict__ nw,    // 512
    bf16* __restrict__ outH,         // 32768 x 512
    bf16* __restrict__ outL)         // 32768 x 512
{
    int row = blockIdx.x * 4 + (threadIdx.x >> 6);
    int lane = threadIdx.x & 63;
    union { uint4 u; bf16 b[8]; } yv, zv, oh, ol;
    yv.u = *(const uint4*)(zx + (size_t)row * 1104 + 512 + lane * 8);
    zv.u = *(const uint4*)(zx + (size_t)row * 1104 + lane * 8);
    float4 nv0 = *(const float4*)(nw + lane * 8);
    float4 nv1 = *(const float4*)(nw + lane * 8 + 4);
    float nvv[8] = {nv0.x, nv0.y, nv0.z, nv0.w, nv1.x, nv1.y, nv1.z, nv1.w};
    float g[8]; float ss = 0.f;
#pragma unroll
    for (int i = 0; i < 8; ++i) {
        float gate = siluf(bf2f(zv.b[i]));
        g[i] = bf2f(yv.b[i]) * gate;
        ss += g[i] * g[i];
    }
#pragma unroll
    for (int o = 1; o < 64; o <<= 1) ss += __shfl_xor(ss, o);
    float rms = rsqrtf(ss * (1.f / 512.f) + EPSF);
#pragma unroll
    for (int i = 0; i < 8; ++i) {
        float v = g[i] * rms * nvv[i];
        bf16 hi = f2bf(v);
        oh.b[i] = hi;
        ol.b[i] = f2bf(v - bf2f(hi));
    }
    *(uint4*)(outH + (size_t)row * 512 + lane * 8) = oh.u;
    *(uint4*)(outL + (size_t)row * 512 + lane * 8) = ol.u;
}

// ---------------------------------------------------------------------------
// h = rmsnorm(mo + h, w) (f32 in/out) + hi/lo planes for next in_proj.
// 4 rows per block, one wave each.
// ---------------------------------------------------------------------------
__global__ __launch_bounds__(256) void resrms_kernel(
    const float* __restrict__ mo,
    float* __restrict__ h,
    const float* __restrict__ w,
    bf16* __restrict__ oH,
    bf16* __restrict__ oL)
{
    int row = blockIdx.x * 4 + (threadIdx.x >> 6);
    int lane = threadIdx.x & 63;
    float4 a = *(const float4*)(mo + (size_t)row * 256 + lane * 4);
    float4 r = *(const float4*)(h  + (size_t)row * 256 + lane * 4);
    float s0 = a.x + r.x, s1 = a.y + r.y, s2 = a.z + r.z, s3 = a.w + r.w;
    float ss = s0 * s0 + s1 * s1 + s2 * s2 + s3 * s3;
#pragma unroll
    for (int o = 1; o < 64; o <<= 1) ss += __shfl_xor(ss, o);
    float rms = rsqrtf(ss * (1.f / 256.f) + EPSF);
    float4 wv = *(const float4*)(w + lane * 4);
    float o0 = s0 * rms * wv.x, o1 = s1 * rms * wv.y;
    float o2 = s2 * rms * wv.z, o3 = s3 * rms * wv.w;
    *(float4*)(h + (size_t)row * 256 + lane * 4) = (float4){o0, o1, o2, o3};
    union { uint2 u; bf16 bb[4]; } uh, ul;
    float o[4] = {o0, o1, o2, o3};
#pragma unroll
    for (int i = 0; i < 4; ++i) {
        bf16 hi = f2bf(o[i]);
        uh.bb[i] = hi;
        ul.bb[i] = f2bf(o[i] - bf2f(hi));
    }
    *(uint2*)(oH + (size_t)row * 256 + lane * 4) = uh.u;
    *(uint2*)(oL + (size_t)row * 256 + lane * 4) = ul.u;
}

// ---------------------------------------------------------------------------
// layernorm over 256 -> hi/lo planes and/or f32. 4 rows per block.
// ---------------------------------------------------------------------------
__global__ __launch_bounds__(256) void ln_kernel(
    const float* __restrict__ x,
    const float* __restrict__ w,
    const float* __restrict__ b,
    bf16* __restrict__ outH,
    bf16* __restrict__ outL,
    float* __restrict__ outF)
{
    int row = blockIdx.x * 4 + (threadIdx.x >> 6);
    int lane = threadIdx.x & 63;
    float4 v = *(const float4*)(x + (size_t)row * 256 + lane * 4);
    float sum = v.x + v.y + v.z + v.w;
    float sq  = v.x * v.x + v.y * v.y + v.z * v.z + v.w * v.w;
#pragma unroll
    for (int o = 1; o < 64; o <<= 1) { sum += __shfl_xor(sum, o); sq += __shfl_xor(sq, o); }
    float m  = sum * (1.f / 256.f);
    float var = sq * (1.f / 256.f) - m * m;
    float is = rsqrtf(var + EPSF);
    float4 wv = *(const float4*)(w + lane * 4);
    float4 bv = *(const float4*)(b + lane * 4);
    float o0 = (v.x - m) * is * wv.x + bv.x;
    float o1 = (v.y - m) * is * wv.y + bv.y;
    float o2 = (v.z - m) * is * wv.z + bv.z;
    float o3 = (v.w - m) * is * wv.w + bv.w;
    if (outH) {
        union { uint2 u; bf16 bb[4]; } oh, ol;
        float o[4] = {o0, o1, o2, o3};
#pragma unroll
        for (int i = 0; i < 4; ++i) {
            bf16 hi = f2bf(o[i]);
            oh.bb[i] = hi;
            ol.bb[i] = f2bf(o[i] - bf2f(hi));
        }
        *(uint2*)(outH + (size_t)row * 256 + lane * 4) = oh.u;
        *(uint2*)(outL + (size_t)row * 256 + lane * 4) = ol.u;
    }
    if (outF)
        *(float4*)(outF + (size_t)row * 256 + lane * 4) = (float4){o0, o1, o2, o3};
}

// ---------------------------------------------------------------------------
extern "C" void kernel_launch(void* const* d_in, const int* in_sizes, int n_in,
                              void* d_out, int out_size, void* d_ws, size_t ws_size,
                              hipStream_t stream)
{
    const float* x      = (const float*)d_in[0];
    const float* ip_w   = (const float*)d_in[1];
    const float* ip_b   = (const float*)d_in[2];
    const float* m_inw  = (const float*)d_in[3];
    const float* m_inb  = (const float*)d_in[4];
    const float* m_convw= (const float*)d_in[5];
    const float* m_convb= (const float*)d_in[6];
    const float* m_dtb  = (const float*)d_in[7];
    const float* m_Alog = (const float*)d_in[8];
    const float* m_D    = (const float*)d_in[9];
    const float* m_nw   = (const float*)d_in[10];
    const float* m_outw = (const float*)d_in[11];
    const float* m_outb = (const float*)d_in[12];
    const float* rms_w  = (const float*)d_in[13];
    const float* ln1_w  = (const float*)d_in[14];
    const float* ln1_b  = (const float*)d_in[15];
    const float* w1     = (const float*)d_in[16];
    const float* b1     = (const float*)d_in[17];
    const float* w2     = (const float*)d_in[18];
    const float* b2     = (const float*)d_in[19];
    const float* ln2_w  = (const float*)d_in[20];
    const float* ln2_b  = (const float*)d_in[21];

    const int M = 32768;   // B * L
    char* wsb = (char*)d_ws;
    size_t off = 0;
    auto alloc = [&](size_t bytes) {
        void* p = wsb + off;
        off += (bytes + 255) & ~(size_t)255;
        return p;
    };
    // ---- activations ----
    bf16*  zx   = (bf16*) alloc((size_t)M * 1104 * 2); // zx bf16; y -> cols[512,1024); mo f32 -> g planes
    float* h    = (float*)alloc((size_t)M * 256 * 4);  // residual stream f32
    float* U1   = (float*)alloc((size_t)M * 512 * 4);  // h planes -> xs f32 -> normed planes -> tb planes
    float* Bc   = (float*)alloc((size_t)M * 32 * 4);
    float* Cc   = (float*)alloc((size_t)M * 32 * 4);
    float* dtf  = (float*)alloc((size_t)M * 16 * 4);
    float* dAf  = (float*)alloc((size_t)M * 16 * 4);
    float* cs   = (float*)alloc((size_t)8192 * 1024 * 4); // chunk states; ubuf in MLP
    float* cpb  = (float*)alloc((size_t)8192 * 4);
    // ---- prepacked weights (hi/lo, transposed [N][K]) ----
    bf16* ipTH   = (bf16*)alloc(262144 * 2);
    bf16* ipTL   = (bf16*)alloc(262144 * 2);
    bf16* inwTH0 = (bf16*)alloc(282624 * 2);
    bf16* inwTL0 = (bf16*)alloc(282624 * 2);
    bf16* inwTH1 = (bf16*)alloc(282624 * 2);
    bf16* inwTL1 = (bf16*)alloc(282624 * 2);
    bf16* outwTH0= (bf16*)alloc(131072 * 2);
    bf16* outwTL0= (bf16*)alloc(131072 * 2);
    bf16* outwTH1= (bf16*)alloc(131072 * 2);
    bf16* outwTL1= (bf16*)alloc(131072 * 2);
    bf16* w1TH   = (bf16*)alloc(131072 * 2);
    bf16* w1TL   = (bf16*)alloc(131072 * 2);
    bf16* w2TH   = (bf16*)alloc(131072 * 2);
    bf16* w2TL   = (bf16*)alloc(131072 * 2);
    (void)ws_size; (void)in_sizes; (void)n_in; (void)out_size;

    float* xs      = U1;
    bf16*  hH      = (bf16*)U1;                 // h hi/lo planes (window: resrms/G1 -> in_proj)
    bf16*  hL      = hH + (size_t)M * 256;
    bf16*  normedH = (bf16*)U1;                 // window: gaterms -> out_proj
    bf16*  normedL = normedH + (size_t)M * 512;
    bf16*  tbH     = (bf16*)U1;                 // window: MLP
    bf16*  tbL     = tbH + (size_t)M * 256;
    float* mo      = (float*)zx;
    bf16*  gH      = (bf16*)zx;
    bf16*  gL      = gH + (size_t)M * 512;
    float* ubuf    = (float*)cs;                // MLP gemm2 output (cs dead by then)

    // ---- prepack all weights (one launch, 7 segments) ----
    PrepackArgs pa;
    pa.W[0] = ip_w;               pa.TH[0] = ipTH;    pa.TL[0] = ipTL;    pa.K[0] = 1024; pa.N[0] = 256;
    pa.W[1] = m_inw;              pa.TH[1] = inwTH0;  pa.TL[1] = inwTL0;  pa.K[1] = 256;  pa.N[1] = 1104;
    pa.W[2] = m_inw + 256*1104;   pa.TH[2] = inwTH1;  pa.TL[2] = inwTL1;  pa.K[2] = 256;  pa.N[2] = 1104;
    pa.W[3] = m_outw;             pa.TH[3] = outwTH0; pa.TL[3] = outwTL0; pa.K[3] = 512;  pa.N[3] = 256;
    pa.W[4] = m_outw + 512*256;   pa.TH[4] = outwTH1; pa.TL[4] = outwTL1; pa.K[4] = 512;  pa.N[4] = 256;
    pa.W[5] = w1;                 pa.TH[5] = w1TH;    pa.TL[5] = w1TL;    pa.K[5] = 256;  pa.N[5] = 512;
    pa.W[6] = w2;                 pa.TH[6] = w2TH;    pa.TL[6] = w2TL;    pa.K[6] = 512;  pa.N[6] = 256;
    prepack_kernel<<<dim3(1104, 7), 256, 0, stream>>>(pa);

    dim3 blk(256);

    // G1: h = x @ ip_w + ip_b   (f32-A path) + hi/lo planes of h
    gemm_hl<<<dim3(256, 4), blk, 0, stream>>>(
        nullptr, nullptr, x, 1024, ipTH, ipTL, ip_b, 256, 1024,
        h, 256, nullptr, 0, hH, hL, 256, 0,
        nullptr, nullptr, nullptr, nullptr);

    for (int L = 0; L < 2; ++L) {
        const bf16* inwTH = L ? inwTH1 : inwTH0;
        const bf16* inwTL = L ? inwTL1 : inwTL0;
        const bf16* outwTH= L ? outwTH1 : outwTH0;
        const bf16* outwTL= L ? outwTL1 : outwTL0;
        const float* inb = m_inb  + (size_t)L * 1104;
        const float* cw  = m_convw+ (size_t)L * 576 * 4;
        const float* cb  = m_convb+ (size_t)L * 576;
        const float* dtb = m_dtb  + L * 16;
        const float* Al  = m_Alog + L * 16;
        const float* Dv  = m_D    + L * 16;
        const float* nw  = m_nw   + (size_t)L * 512;
        const float* ob  = m_outb + (size_t)L * 256;
        const float* rw  = rms_w  + (size_t)L * 256;

        // in_proj: zx = h @ inw + inb (plane-A path), fused dt -> dtf/dAf
        gemm_hl<<<dim3(256, 18), blk, 0, stream>>>(
            hH, hL, nullptr, 256, inwTH, inwTL, inb, 1104, 256,
            nullptr, 0, zx, 1104, nullptr, nullptr, 0, 0,
            dtb, Al, dtf, dAf);
        conv_kernel<<<9216, 256, 0, stream>>>(zx, cw, cb, xs, Bc, Cc);
        scan_phase1<<<2048, 256, 0, stream>>>(xs, Bc, dtf, dAf, cs, cpb);
        scan_phase2<<<256, 64, 0, stream>>>(cs, cpb);
        scan_phase3<<<2048, 256, 0, stream>>>(xs, Bc, Cc, dtf, dAf, Dv, cs, zx);
        gaterms_kernel<<<M / 4, 256, 0, stream>>>(zx, nw, normedH, normedL);
        // out_proj: mo = normed @ outw + outb (plane-A)
        gemm_hl<<<dim3(256, 4), blk, 0, stream>>>(
            normedH, normedL, nullptr, 512, outwTH, outwTL, ob, 256, 512,
            mo, 256, nullptr, 0, nullptr, nullptr, 0, 0,
            nullptr, nullptr, nullptr, nullptr);
        resrms_kernel<<<M / 4, 256, 0, stream>>>(mo, h, rw, hH, hL);
    }

    // MLP head
    ln_kernel<<<M / 4, 256, 0, stream>>>(h, ln1_w, ln1_b, tbH, tbL, nullptr);
    gemm_hl<<<dim3(256, 8), blk, 0, stream>>>(
        tbH, tbL, nullptr, 256, w1TH, w1TL, b1, 512, 256,
        nullptr, 0, nullptr, 0, gH, gL, 512, 1,
        nullptr, nullptr, nullptr, nullptr);
    gemm_hl<<<dim3(256, 4), blk, 0, stream>>>(
        gH, gL, nullptr, 512, w2TH, w2TL, b2, 256, 512,
        ubuf, 256, nullptr, 0, nullptr, nullptr, 0, 0,
        nullptr, nullptr, nullptr, nullptr);
    ln_kernel<<<M / 4, 256, 0, stream>>>(ubuf, ln2_w, ln2_b, nullptr, nullptr, (float*)d_out);
}